// Round 2
// 463.150 us; speedup vs baseline: 1.0340x; 1.0340x over previous
//
#include <hip/hip_runtime.h>

// WeaveLayer: pure permutation.
//   out[b, yb*8 + hi*4 + px, xb*8 + wi*4 + py] = imgs[b, yb*4+py, xb*4+px, hi*2+wi]
// imgs (32,768,768,4) f32 -> out (32,1536,1536,1) f32. 604 MB total traffic.
//
// v3b: identical dataflow to v3; compile fix only. __builtin_nontemporal_*
// requires a clang vector type, not HIP's float4 class -> use a native
// ext_vector_type(4) float alias (identical 16B layout) everywhere.
//
// v3 changes vs v2 (the 480us baseline):
//   1. __syncthreads() removed. Each wave only ever touches its own LDS
//      slice; same-wave DS ops complete in order, so the block barrier was
//      pure convoy overhead. sched_barrier(0) is a compile-time fence only.
//   2. 2 yb-groups per block: grid 18432 -> 9216, 8 global loads in flight
//      up-front per thread (128B in / 128B out per thread).
//   3. Nontemporal load/store hints: zero-reuse streaming op.
//
// LDS row stride 33 float4s (S % 8 == 1) -> phase-1 scattered writes and
// phase-2 contiguous reads both spread uniformly over the 8 16B granules
// (the b128 minimum): conflict-free.
// LDS = 2 * 4 * 8 * 33 * 16B = 33 KB -> 4 blocks/CU = 16 waves/CU resident.

#define B_   32
#define Y_   768
#define X_   768
#define YB_  192   // Y_/4
#define OW4_ 384   // (2*X_)/4 : output row length in float4s
#define S_   33    // LDS row stride in float4s (32 + 1 pad)

typedef float f4 __attribute__((ext_vector_type(4)));

__global__ __launch_bounds__(256) void weave_kernel(
    const f4* __restrict__ in, f4* __restrict__ out)
{
    __shared__ f4 lds[2][4 * 8 * S_];   // 2 groups x 4 waves x 8 rows x 33

    const int tid  = threadIdx.x;
    const int gid  = blockIdx.x;

    const int xblk = gid % 3;            // 768 / 256 = 3 blocks span x
    const int byp  = gid / 3;
    const int ybp  = byp % (YB_ / 2);    // yb-pair index
    const int b    = byp / (YB_ / 2);
    const int yb0  = ybp * 2;

    const int w = tid >> 6;              // wave id 0..3
    const int l = tid & 63;              // lane
    const int px = l & 3;
    const int xo = l >> 2;               // 0..15: xb offset within wave

    // ---- Phase 1: issue all 8 coalesced loads (2 groups x 4 rows) up-front
    const int x = xblk * 256 + tid;      // 0..767
    const long ibase = ((long)(b * Y_ + yb0 * 4) * X_ + x);

    f4 r[2][4];
    #pragma unroll
    for (int g = 0; g < 2; ++g)
        #pragma unroll
        for (int j = 0; j < 4; ++j)
            r[g][j] = __builtin_nontemporal_load(&in[ibase + (long)(g * 4 + j) * X_]);

    // ---- register 4x4 transpose -> wave-private LDS tiles (output order)
    #pragma unroll
    for (int g = 0; g < 2; ++g) {
        f4* wlds = &lds[g][w * (8 * S_)];
        wlds[ px      * S_ + xo * 2    ] = (f4){r[g][0].x, r[g][1].x, r[g][2].x, r[g][3].x}; // hi0 wi0
        wlds[ px      * S_ + xo * 2 + 1] = (f4){r[g][0].y, r[g][1].y, r[g][2].y, r[g][3].y}; // hi0 wi1
        wlds[(px + 4) * S_ + xo * 2    ] = (f4){r[g][0].z, r[g][1].z, r[g][2].z, r[g][3].z}; // hi1 wi0
        wlds[(px + 4) * S_ + xo * 2 + 1] = (f4){r[g][0].w, r[g][1].w, r[g][2].w, r[g][3].w}; // hi1 wi1
    }

    // Wave-private data: no block barrier needed. Compile-time fence only
    // (prevents the scheduler from hoisting phase-2 ds_reads above writes;
    // the compiler's lgkmcnt tracking handles the data dependency).
    __builtin_amdgcn_sched_barrier(0);

    // ---- Phase 2: contiguous LDS reads -> dense global stores
    // Wave w owns out rows (yb0+g)*8+[0,8), col4 range [xblk*128 + w*32, +32).
    #pragma unroll
    for (int g = 0; g < 2; ++g) {
        const long obase = (long)(b * 1536 + (yb0 + g) * 8) * OW4_ + xblk * 128 + w * 32;
        const f4* wlds = &lds[g][w * (8 * S_)];
        #pragma unroll
        for (int jj = 0; jj < 4; ++jj) {
            const int flat = jj * 64 + l;
            const int row8 = flat >> 5;      // 0..7 = hi*4+px
            const int c    = flat & 31;      // col4 within wave segment
            __builtin_nontemporal_store(wlds[row8 * S_ + c],
                                        &out[obase + (long)row8 * OW4_ + c]);
        }
    }
}

extern "C" void kernel_launch(void* const* d_in, const int* in_sizes, int n_in,
                              void* d_out, int out_size, void* d_ws, size_t ws_size,
                              hipStream_t stream) {
    (void)in_sizes; (void)n_in; (void)d_ws; (void)ws_size; (void)out_size;
    const f4* imgs = (const f4*)d_in[0];  // (32,768,768,4) f32, 16B px groups
    f4* out = (f4*)d_out;                 // (32,1536,1536,1) f32

    const int grid = B_ * (YB_ / 2) * 3;  // 9216 blocks of 256
    weave_kernel<<<grid, 256, 0, stream>>>(imgs, out);
}